// Round 4
// baseline (478.092 us; speedup 1.0000x reference)
//
#include <hip/hip_runtime.h>
#include <math.h>

namespace {
constexpr int NB = 4, NCHT = 29, NF = 19, NM = 7, NHI = 3;
constexpr int HH = 512, WW = 512;
constexpr int PH  = 170;           // pooled H/W (512-3)/3+1
constexpr int NHW = 168;           // shifted-view grid 170-3+1
constexpr int NS  = NHW * NHW;     // 28224 samples
constexpr int NBC = NB * NCHT;     // 116 (b,c) pairs
constexpr int NCHUNK = 16;
constexpr int CHS = NS / NCHUNK;   // 1764
constexpr int S1CH = 8;
constexpr int S1N  = NS / S1CH;    // 3528

constexpr int F2M[NF] = {0,0,0,1,1,1,2,2,3,3,4,5,5,6,6,6,6,6,6};
constexpr int M2H[NM] = {0,0,1,1,1,2,2};
constexpr int F2H[NF] = {0,0,0,0,0,0,1,1,1,1,1,2,2,2,2,2,2,2,2};

constexpr unsigned long long packTbl(const int* a, int n) {
  unsigned long long p = 0;
  for (int i = 0; i < n; i++) p |= (unsigned long long)(a[i]) << (3 * i);
  return p;
}
constexpr unsigned long long PF2M = packTbl(F2M, NF);
constexpr unsigned long long PF2H = packTbl(F2H, NF);

// ws float layout
constexpr int    WS_S1  = 16;    // 116*32
constexpr int    WS_COV = 4096;  // 116*324
constexpr size_t WS_LA  = 65536;
constexpr size_t WS_PR  = WS_LA + (size_t)NBC * PH * PH;
constexpr size_t WS_ZERO_BYTES = (size_t)(WS_COV + NBC * 324) * 4;
} // namespace

// ---------------- kernel A: per-column sigmoid + hierarchy + BCE + 3x3 pool --
// grid (5, 171, NB), block 128. Block bx owns windows [34*bx, 34*bx+34),
// i.e. columns [102*bx, 102*bx+102). Each thread: exactly one column.
// bx==4: threads 102,103 additionally cover BCE-only columns 510,511.
__global__ __launch_bounds__(128, 4)
void kA(const float* __restrict__ cls, const int* __restrict__ label,
        float* __restrict__ ws) {
  const int bx  = blockIdx.x;
  const int wy  = blockIdx.y;
  const int b   = blockIdx.z;
  const int tid = threadIdx.x;
  const int col0 = 102 * bx;
  const int ny   = (wy == 170) ? 2 : 3;

  __shared__ float    sPr[102][30];   // 29 used, stride 30
  __shared__ unsigned sMask[102];

  float bce0 = 0.f, bce1 = 0.f, bce2 = 0.f, cnt = 0.f;

  const bool pool   = (tid < 102);
  const bool hasCol = pool || (bx == 4 && tid < 104);

  if (hasCol) {
    const int x = col0 + tid;
    float colPr[NCHT];
    #pragma unroll
    for (int c = 0; c < NCHT; c++) colPr[c] = 0.f;
    unsigned msk = 0u;

    for (int dy = 0; dy < ny; dy++) {
      const int y = 3 * wy + dy;
      const int lbl = label[((size_t)b * HH + y) * WW + x];
      const bool valid = (lbl != 255);
      const int lf = valid ? lbl : 0;
      const int lm = (int)((PF2M >> (3 * lf)) & 7ull);
      const int lh = (int)((PF2H >> (3 * lf)) & 7ull);
      const float vm = valid ? 1.f : 0.f;

      const float* cp = cls + ((size_t)(b * NCHT) * HH + y) * WW + x;
      float p[NCHT];
      #pragma unroll
      for (int c = 0; c < NCHT; c++)
        p[c] = __builtin_amdgcn_rcpf(1.f + __expf(-cp[(size_t)c * HH * WW]));

      float segf[NM];
      #pragma unroll
      for (int m = 0; m < NM; m++) segf[m] = -1.f;
      #pragma unroll
      for (int f = 0; f < NF; f++) segf[F2M[f]] = fmaxf(segf[F2M[f]], p[f]);
      float pBc[NM];
      #pragma unroll
      for (int m = 0; m < NM; m++) pBc[m] = fmaxf(segf[m], p[NF + m]);
      float segm[NHI];
      #pragma unroll
      for (int k = 0; k < NHI; k++) segm[k] = -1.f;
      #pragma unroll
      for (int m = 0; m < NM; m++) segm[M2H[m]] = fmaxf(segm[M2H[m]], pBc[m]);
      float pCc[NHI];
      #pragma unroll
      for (int k = 0; k < NHI; k++) pCc[k] = fmaxf(segm[k], p[NF + NM + k]);

      // fine: pos = min(pA, pB[f2m]), neg = pA
      #pragma unroll
      for (int f = 0; f < NF; f++) {
        const float pos = fminf(p[f], p[NF + F2M[f]]);
        if (valid)
          bce0 += (f == lf) ? -__logf(pos + 1e-8f) : -__logf(1.f - p[f] + 1e-8f);
        colPr[f] = fmaxf(colPr[f], pos * vm + 1e-6f);
      }
      // mid: pos = min(pB, pC[m2h]), neg = pBc
      #pragma unroll
      for (int m = 0; m < NM; m++) {
        const float pos = fminf(p[NF + m], p[NF + NM + M2H[m]]);
        if (valid)
          bce1 += (m == lm) ? -__logf(pos + 1e-8f) : -__logf(1.f - pBc[m] + 1e-8f);
        colPr[NF + m] = fmaxf(colPr[NF + m], pos * vm + 1e-6f);
      }
      // high: pos = pC, neg = pCc
      #pragma unroll
      for (int k = 0; k < NHI; k++) {
        const float pos = p[NF + NM + k];
        if (valid)
          bce2 += (k == lh) ? -__logf(pos + 1e-8f) : -__logf(1.f - pCc[k] + 1e-8f);
        colPr[NF + NM + k] = fmaxf(colPr[NF + NM + k], pos * vm + 1e-6f);
      }
      if (valid) {
        msk |= 1u << lf;
        msk |= 1u << (19 + lm);
        msk |= 1u << (26 + lh);
      }
      cnt += vm;
    }
    if (pool) {
      sMask[tid] = msk;
      #pragma unroll
      for (int c = 0; c < NCHT; c++) sPr[tid][c] = colPr[c];
    }
  }
  __syncthreads();

  if (wy < 170 && tid < 34) {
    const int wx = 34 * bx + tid;
    const int c0 = 3 * tid;
    float* la = ws + WS_LA;
    float* pr = ws + WS_PR;
    const unsigned m = sMask[c0] | sMask[c0 + 1] | sMask[c0 + 2];
    const size_t base = ((size_t)(b * NCHT) * PH + wy) * PH + wx;
    #pragma unroll
    for (int c = 0; c < NF; c++)
      la[base + (size_t)c * PH * PH] = (float)((m >> c) & 1u);
    #pragma unroll
    for (int mm = 0; mm < NM; mm++)
      la[base + (size_t)(NF + mm) * PH * PH] = (float)((m >> (19 + mm)) & 1u);
    #pragma unroll
    for (int k = 0; k < NHI; k++)
      la[base + (size_t)(NF + NM + k) * PH * PH] = (float)((m >> (26 + k)) & 1u);
    #pragma unroll
    for (int c = 0; c < NCHT; c++)
      pr[base + (size_t)c * PH * PH] =
          fmaxf(fmaxf(sPr[c0][c], sPr[c0 + 1][c]), sPr[c0 + 2][c]);
  }

  #pragma unroll
  for (int m = 32; m >= 1; m >>= 1) {
    bce0 += __shfl_xor(bce0, m);
    bce1 += __shfl_xor(bce1, m);
    bce2 += __shfl_xor(bce2, m);
    cnt  += __shfl_xor(cnt, m);
  }
  if ((tid & 63) == 0) {
    atomicAdd(&ws[0], bce0);
    atomicAdd(&ws[1], bce1);
    atomicAdd(&ws[2], bce2);
    atomicAdd(&ws[3], cnt);
  }
}

// ---------------- kernel S1: per-(b,c) sums of the 18 shifted views (chunked)-
__global__ __launch_bounds__(256)
void kS1(const float* __restrict__ ws_base, float* __restrict__ s1out) {
  const int bc    = blockIdx.x / S1CH;
  const int chunk = blockIdx.x % S1CH;
  const float* A = ws_base + WS_LA + (size_t)bc * PH * PH;
  const float* P = ws_base + WS_PR + (size_t)bc * PH * PH;
  float sums[18];
  #pragma unroll
  for (int r = 0; r < 18; r++) sums[r] = 0.f;
  const int s0 = chunk * S1N;
  for (int s = s0 + threadIdx.x; s < s0 + S1N; s += 256) {
    const int sy = s / NHW, sx = s - sy * NHW;
    const int idx = sy * PH + sx;
    #pragma unroll
    for (int r = 0; r < 9; r++) sums[r] += A[idx + (r / 3) * PH + (r % 3)];
    #pragma unroll
    for (int r = 0; r < 9; r++) sums[9 + r] += P[idx + (r / 3) * PH + (r % 3)];
  }
  #pragma unroll
  for (int r = 0; r < 18; r++) {
    float v = sums[r];
    #pragma unroll
    for (int m = 32; m >= 1; m >>= 1) v += __shfl_xor(v, m);
    sums[r] = v;
  }
  __shared__ float lds[4][18];
  const int wave = threadIdx.x >> 6, lane = threadIdx.x & 63;
  if (lane == 0) {
    #pragma unroll
    for (int r = 0; r < 18; r++) lds[wave][r] = sums[r];
  }
  __syncthreads();
  if (threadIdx.x < 18)
    atomicAdd(&s1out[bc * 32 + threadIdx.x],
              lds[0][threadIdx.x] + lds[1][threadIdx.x] +
              lds[2][threadIdx.x] + lds[3][threadIdx.x]);
}

// ---------------- kernel Cov: CENTERED 18x18 second moments, 6x6 reg tiles --
__global__ __launch_bounds__(192)
void kCov(const float* __restrict__ ws_base, const float* __restrict__ s1,
          float* __restrict__ cov) {
  const int bc    = blockIdx.x / NCHUNK;
  const int chunk = blockIdx.x % NCHUNK;
  const int tile  = threadIdx.x / 32;
  const int g     = threadIdx.x % 32;
  // tiles: 0:(0,0) 1:(0,1) 2:(0,2) 3:(1,1) 4:(1,2) 5:(2,2)
  const int ta = (tile < 3) ? 0 : ((tile < 5) ? 1 : 2);
  const int tb = (tile < 3) ? tile : ((tile < 5) ? tile - 2 : 2);
  const float* Abase = ws_base + WS_LA + (size_t)bc * PH * PH;
  const float* Pbase = ws_base + WS_PR + (size_t)bc * PH * PH;
  const float inv_n = 1.0f / (float)NS;

  const float* pA[6];
  const float* pB[6];
  float muA[6], muB[6];
  #pragma unroll
  for (int k = 0; k < 6; k++) {
    int r = 6 * ta + k; int rr = (r < 9) ? r : r - 9;
    pA[k]  = ((r < 9) ? Abase : Pbase) + (rr / 3) * PH + (rr % 3);
    muA[k] = s1[bc * 32 + r] * inv_n;
    int r2 = 6 * tb + k; int rr2 = (r2 < 9) ? r2 : r2 - 9;
    pB[k]  = ((r2 < 9) ? Abase : Pbase) + (rr2 / 3) * PH + (rr2 % 3);
    muB[k] = s1[bc * 32 + r2] * inv_n;
  }

  float acc[6][6];
  #pragma unroll
  for (int k = 0; k < 6; k++)
    #pragma unroll
    for (int l = 0; l < 6; l++) acc[k][l] = 0.f;

  int s = chunk * CHS + g;
  const int send = chunk * CHS + CHS;
  int sy = s / NHW, sx = s - sy * NHW;
  for (; s < send; s += 32) {
    const int idx = sy * PH + sx;
    float va[6], vb[6];
    #pragma unroll
    for (int k = 0; k < 6; k++) { va[k] = pA[k][idx] - muA[k]; vb[k] = pB[k][idx] - muB[k]; }
    #pragma unroll
    for (int k = 0; k < 6; k++)
      #pragma unroll
      for (int l = 0; l < 6; l++) acc[k][l] = fmaf(va[k], vb[l], acc[k][l]);
    sx += 32; if (sx >= NHW) { sx -= NHW; sy++; }
  }

  #pragma unroll
  for (int k = 0; k < 6; k++)
    #pragma unroll
    for (int l = 0; l < 6; l++) {
      float v = acc[k][l];
      #pragma unroll
      for (int m = 16; m >= 1; m >>= 1) v += __shfl_xor(v, m);
      acc[k][l] = v;
    }
  if (g == 0) {
    float* dst = cov + (size_t)bc * 324;
    #pragma unroll
    for (int k = 0; k < 6; k++)
      #pragma unroll
      for (int l = 0; l < 6; l++)
        atomicAdd(&dst[(6 * ta + k) * 18 + 6 * tb + l], acc[k][l]);
  }
}

// ---------------- kernel Solve: one wave per (b,c), row-distributed 9x9 ------
// cov upper-triangle convention: C(i,j) = cov[min*18+max]
__global__ __launch_bounds__(64)
void kSolve(const float* __restrict__ cov_all, float* __restrict__ acc) {
  const int bc   = blockIdx.x;
  const int lane = threadIdx.x;
  const float* cr = cov_all + (size_t)bc * 324;

  // --- Cholesky of P = pr_cov + 1e-3 I ; lane i holds row i (j<=i) ----------
  double row[9];
  #pragma unroll
  for (int j = 0; j < 9; j++)
    row[j] = (lane < 9 && j <= lane) ? (double)cr[(9 + j) * 18 + (9 + lane)] : 0.0;
  if (lane < 9) row[lane] += 1e-3;

  #pragma unroll
  for (int k = 0; k < 9; k++) {
    if (lane == k) {
      double s = row[k];
      #pragma unroll
      for (int m = 0; m < k; m++) s -= row[m] * row[m];
      row[k] = sqrt(fmax(s, 1e-300));
    }
    double rk[9];
    #pragma unroll
    for (int m = 0; m <= k; m++) rk[m] = __shfl(row[m], k);
    if (lane > k && lane < 9) {
      double s = row[k];
      #pragma unroll
      for (int m = 0; m < k; m++) s -= row[m] * rk[m];
      row[k] = s / rk[k];
    }
  }

  // --- gather full L into each lane -----------------------------------------
  double Lm[9][9];
  #pragma unroll
  for (int i = 0; i < 9; i++)
    #pragma unroll
    for (int m = 0; m <= i; m++) Lm[i][m] = __shfl(row[m], i);

  // --- lane c solves L * mc = B^T[:,c], B[c][r] = C(c, 9+r) -----------------
  double mc[9];
  #pragma unroll
  for (int r = 0; r < 9; r++) mc[r] = 0.0;
  if (lane < 9) {
    #pragma unroll
    for (int r = 0; r < 9; r++) {
      double s = (double)cr[lane * 18 + 9 + r];
      #pragma unroll
      for (int m = 0; m < r; m++) s -= Lm[r][m] * mc[m];
      mc[r] = s / Lm[r][r];
    }
  }

  // --- A2[i][j] = C(j,i) - dot(m_i, m_j) (+1e-3 diag); lane i holds row i ---
  double a2[9];
  #pragma unroll
  for (int j = 0; j < 9; j++) a2[j] = 0.0;
  #pragma unroll
  for (int j = 0; j < 9; j++) {
    double mj[9];
    #pragma unroll
    for (int r = 0; r < 9; r++) mj[r] = __shfl(mc[r], j);
    double dot = 0.0;
    #pragma unroll
    for (int r = 0; r < 9; r++) dot += mc[r] * mj[r];
    if (lane < 9 && j <= lane)
      a2[j] = (double)cr[j * 18 + lane] - dot + ((j == lane) ? 1e-3 : 0.0);
  }

  // --- second Cholesky + logdet ---------------------------------------------
  double myld = 0.0;
  #pragma unroll
  for (int k = 0; k < 9; k++) {
    if (lane == k) {
      double s = a2[k];
      #pragma unroll
      for (int m = 0; m < k; m++) s -= a2[m] * a2[m];
      double d = sqrt(fmax(s, 0.0));
      a2[k] = d;
      myld = 2.0 * log(d + 1e-8);
    }
    double rk[9];
    #pragma unroll
    for (int m = 0; m <= k; m++) rk[m] = __shfl(a2[m], k);
    if (lane > k && lane < 9) {
      double s = a2[k];
      #pragma unroll
      for (int m = 0; m < k; m++) s -= a2[m] * rk[m];
      a2[k] = s / rk[k];
    }
  }
  #pragma unroll
  for (int m = 32; m >= 1; m >>= 1) myld += __shfl_xor(myld, m);
  if (lane == 0) atomicAdd(&acc[4], (float)myld);
}

// ---------------- finalize ----------------------------------------------------
__global__ void kFin(const float* __restrict__ ws, float* __restrict__ out) {
  if (threadIdx.x == 0 && blockIdx.x == 0) {
    const double cnt = (double)ws[3];
    const double bce = 0.5 * ((double)ws[0] / (cnt * NF + 1e-8) +
                              (double)ws[1] / (cnt * NM + 1e-8) +
                              (double)ws[2] / (cnt * NHI + 1e-8));
    const double rmi = 0.5 * (double)ws[4] / (double)(NB * 9);
    out[0] = (float)(bce + rmi);
  }
}

extern "C" void kernel_launch(void* const* d_in, const int* in_sizes, int n_in,
                              void* d_out, int out_size, void* d_ws, size_t ws_size,
                              hipStream_t stream) {
  (void)in_sizes; (void)n_in; (void)out_size; (void)ws_size;
  const float* cls   = (const float*)d_in[3];
  const int*   label = (const int*)d_in[4];
  float* ws = (float*)d_ws;

  hipMemsetAsync(d_ws, 0, WS_ZERO_BYTES, stream);

  dim3 gA(5, 171, NB);
  kA<<<gA, 128, 0, stream>>>(cls, label, ws);
  kS1<<<NBC * S1CH, 256, 0, stream>>>(ws, ws + WS_S1);
  kCov<<<NBC * NCHUNK, 192, 0, stream>>>(ws, ws + WS_S1, ws + WS_COV);
  kSolve<<<NBC, 64, 0, stream>>>(ws + WS_COV, ws);
  kFin<<<1, 64, 0, stream>>>(ws, (float*)d_out);
}

// Round 5
// 450.215 us; speedup vs baseline: 1.0619x; 1.0619x over previous
//
#include <hip/hip_runtime.h>
#include <math.h>

namespace {
constexpr int NB = 4, NCHT = 29, NF = 19, NM = 7, NHI = 3;
constexpr int HH = 512, WW = 512;
constexpr int PH  = 170;           // pooled H/W (512-3)/3+1
constexpr int NHW = 168;           // shifted-view grid 170-3+1
constexpr int NS  = NHW * NHW;     // 28224 samples
constexpr int NBC = NB * NCHT;     // 116 (b,c) pairs
constexpr int CROWS = 14;          // sample rows per kCov chunk
constexpr int NCH2  = NHW / CROWS; // 12 chunks

constexpr int F2M[NF] = {0,0,0,1,1,1,2,2,3,3,4,5,5,6,6,6,6,6,6};
constexpr int M2H[NM] = {0,0,1,1,1,2,2};
constexpr int F2H[NF] = {0,0,0,0,0,0,1,1,1,1,1,2,2,2,2,2,2,2,2};

constexpr unsigned long long packTbl(const int* a, int n) {
  unsigned long long p = 0;
  for (int i = 0; i < n; i++) p |= (unsigned long long)(a[i]) << (3 * i);
  return p;
}
constexpr unsigned long long PF2M = packTbl(F2M, NF);
constexpr unsigned long long PF2H = packTbl(F2H, NF);

// ws float layout
constexpr int    WS_S1  = 16;    // raw view sums, 116*32
constexpr int    WS_COV = 4096;  // raw upper-tri moments, 116*324
constexpr size_t WS_LA  = 65536;
constexpr size_t WS_PR  = WS_LA + (size_t)NBC * PH * PH;
constexpr size_t WS_ZERO_BYTES = (size_t)(WS_COV + NBC * 324) * 4;
} // namespace

// ---------------- kernel A: per-column sigmoid + hierarchy + BCE + 3x3 pool --
// grid (5, 171, NB), block 128. Block bx owns windows [34bx,34bx+34) i.e.
// columns [102bx, 102bx+102); thread = one column, 3 rows loaded UP FRONT
// (~90 independent loads in flight -> latency hidden). bx==4: tid 102,103
// cover BCE-only columns 510,511.
__global__ __launch_bounds__(128, 2)
void kA(const float* __restrict__ cls, const int* __restrict__ label,
        float* __restrict__ ws) {
  const int bx  = blockIdx.x;
  const int wy  = blockIdx.y;
  const int b   = blockIdx.z;
  const int tid = threadIdx.x;

  __shared__ float    sPr[102][30];   // 29 used, stride 30
  __shared__ unsigned sMask[102];

  float bce0 = 0.f, bce1 = 0.f, bce2 = 0.f, cnt = 0.f;

  const bool pool   = (tid < 102);
  const bool hasCol = pool || (bx == 4 && tid < 104);
  const bool row2   = (wy < 170);     // wy==170: only 2 real rows

  if (hasCol) {
    const int x  = 102 * bx + tid;
    const int y0 = 3 * wy;
    const size_t lpix = ((size_t)b * HH + y0) * WW + x;
    const int off2 = row2 ? 2 * WW : 0;   // safe dummy addr for wy==170
    const int l0 = label[lpix];
    const int l1 = label[lpix + WW];
    const int l2 = label[lpix + off2];

    const float* cp = cls + ((size_t)(b * NCHT) * HH + y0) * WW + x;
    float r0v[NCHT], r1v[NCHT], r2v[NCHT];
    #pragma unroll
    for (int c = 0; c < NCHT; c++) r0v[c] = cp[(size_t)c * HH * WW];
    #pragma unroll
    for (int c = 0; c < NCHT; c++) r1v[c] = cp[(size_t)c * HH * WW + WW];
    #pragma unroll
    for (int c = 0; c < NCHT; c++) r2v[c] = cp[(size_t)c * HH * WW + off2];

    float colPr[NCHT];
    #pragma unroll
    for (int c = 0; c < NCHT; c++) colPr[c] = 0.f;
    unsigned msk = 0u;

    auto doRow = [&](const float* rv, int lbl, bool act) {
      const bool valid = act && (lbl != 255);
      const int lf = valid ? lbl : 0;
      const int lm = (int)((PF2M >> (3 * lf)) & 7ull);
      const int lh = (int)((PF2H >> (3 * lf)) & 7ull);
      const float vm = valid ? 1.f : 0.f;

      float p[NCHT];
      #pragma unroll
      for (int c = 0; c < NCHT; c++)
        p[c] = __builtin_amdgcn_rcpf(1.f + __expf(-rv[c]));

      float segf[NM];
      #pragma unroll
      for (int m = 0; m < NM; m++) segf[m] = -1.f;
      #pragma unroll
      for (int f = 0; f < NF; f++) segf[F2M[f]] = fmaxf(segf[F2M[f]], p[f]);
      float pBc[NM];
      #pragma unroll
      for (int m = 0; m < NM; m++) pBc[m] = fmaxf(segf[m], p[NF + m]);
      float segm[NHI];
      #pragma unroll
      for (int k = 0; k < NHI; k++) segm[k] = -1.f;
      #pragma unroll
      for (int m = 0; m < NM; m++) segm[M2H[m]] = fmaxf(segm[M2H[m]], pBc[m]);
      float pCc[NHI];
      #pragma unroll
      for (int k = 0; k < NHI; k++) pCc[k] = fmaxf(segm[k], p[NF + NM + k]);

      // fine: pos = min(pA, pB[f2m]), neg = pA
      #pragma unroll
      for (int f = 0; f < NF; f++) {
        const float pos = fminf(p[f], p[NF + F2M[f]]);
        if (valid)
          bce0 += (f == lf) ? -__logf(pos + 1e-8f) : -__logf(1.f - p[f] + 1e-8f);
        colPr[f] = fmaxf(colPr[f], pos * vm + 1e-6f);
      }
      // mid: pos = min(pB, pC[m2h]), neg = pBc
      #pragma unroll
      for (int m = 0; m < NM; m++) {
        const float pos = fminf(p[NF + m], p[NF + NM + M2H[m]]);
        if (valid)
          bce1 += (m == lm) ? -__logf(pos + 1e-8f) : -__logf(1.f - pBc[m] + 1e-8f);
        colPr[NF + m] = fmaxf(colPr[NF + m], pos * vm + 1e-6f);
      }
      // high: pos = pC, neg = pCc
      #pragma unroll
      for (int k = 0; k < NHI; k++) {
        const float pos = p[NF + NM + k];
        if (valid)
          bce2 += (k == lh) ? -__logf(pos + 1e-8f) : -__logf(1.f - pCc[k] + 1e-8f);
        colPr[NF + NM + k] = fmaxf(colPr[NF + NM + k], pos * vm + 1e-6f);
      }
      if (valid) {
        msk |= 1u << lf;
        msk |= 1u << (19 + lm);
        msk |= 1u << (26 + lh);
      }
      cnt += vm;
    };

    doRow(r0v, l0, true);
    doRow(r1v, l1, true);
    doRow(r2v, l2, row2);

    if (pool) {
      sMask[tid] = msk;
      #pragma unroll
      for (int c = 0; c < NCHT; c++) sPr[tid][c] = colPr[c];
    }
  }
  __syncthreads();

  if (row2 && tid < 34) {
    const int wx = 34 * bx + tid;
    const int c0 = 3 * tid;
    float* la = ws + WS_LA;
    float* pr = ws + WS_PR;
    const unsigned m = sMask[c0] | sMask[c0 + 1] | sMask[c0 + 2];
    const size_t base = ((size_t)(b * NCHT) * PH + wy) * PH + wx;
    #pragma unroll
    for (int c = 0; c < NF; c++)
      la[base + (size_t)c * PH * PH] = (float)((m >> c) & 1u);
    #pragma unroll
    for (int mm = 0; mm < NM; mm++)
      la[base + (size_t)(NF + mm) * PH * PH] = (float)((m >> (19 + mm)) & 1u);
    #pragma unroll
    for (int k = 0; k < NHI; k++)
      la[base + (size_t)(NF + NM + k) * PH * PH] = (float)((m >> (26 + k)) & 1u);
    #pragma unroll
    for (int c = 0; c < NCHT; c++)
      pr[base + (size_t)c * PH * PH] =
          fmaxf(fmaxf(sPr[c0][c], sPr[c0 + 1][c]), sPr[c0 + 2][c]);
  }

  #pragma unroll
  for (int m = 32; m >= 1; m >>= 1) {
    bce0 += __shfl_xor(bce0, m);
    bce1 += __shfl_xor(bce1, m);
    bce2 += __shfl_xor(bce2, m);
    cnt  += __shfl_xor(cnt, m);
  }
  if ((tid & 63) == 0) {
    atomicAdd(&ws[0], bce0);
    atomicAdd(&ws[1], bce1);
    atomicAdd(&ws[2], bce2);
    atomicAdd(&ws[3], cnt);
  }
}

// ---------------- kernel Cov: RAW 18x18 moments + view sums, LDS stencil ----
// The 9 "views" of a plane are a 3x3 stencil: stage 16 plane rows in LDS once,
// read shifted. block = (bc, 14-row chunk), 192 thr = 6 tile-groups x 32.
__global__ __launch_bounds__(192)
void kCov(const float* __restrict__ ws_base, float* __restrict__ cov,
          float* __restrict__ s1out) {
  const int bc    = blockIdx.x / NCH2;
  const int chunk = blockIdx.x % NCH2;
  const int tid   = threadIdx.x;
  const int tile  = tid / 32;
  const int g     = tid % 32;
  // tiles: 0:(0,0) 1:(0,1) 2:(0,2) 3:(1,1) 4:(1,2) 5:(2,2)
  const int ta = (tile < 3) ? 0 : ((tile < 5) ? 1 : 2);
  const int tb = (tile < 3) ? tile : ((tile < 5) ? tile - 2 : 2);
  const bool diag = (ta == tb);

  __shared__ float sA[16 * PH];
  __shared__ float sP[16 * PH];

  const int r0 = chunk * CROWS;
  const float* Ag = ws_base + WS_LA + (size_t)bc * PH * PH + (size_t)r0 * PH;
  const float* Pg = ws_base + WS_PR + (size_t)bc * PH * PH + (size_t)r0 * PH;
  for (int i = tid; i < 16 * PH; i += 192) { sA[i] = Ag[i]; sP[i] = Pg[i]; }
  __syncthreads();

  // view r: plane (r<9 ? A : P), row-offset (r%9)/3, col-offset (r%9)%3
  const float* baseA[6];
  const float* baseB[6];
  #pragma unroll
  for (int k = 0; k < 6; k++) {
    int r = 6 * ta + k, rr = r % 9;
    baseA[k] = ((r < 9) ? sA : sP) + (rr / 3) * PH + (rr % 3);
    int r2 = 6 * tb + k, rr2 = r2 % 9;
    baseB[k] = ((r2 < 9) ? sA : sP) + (rr2 / 3) * PH + (rr2 % 3);
  }

  float acc[6][6];
  #pragma unroll
  for (int k = 0; k < 6; k++)
    #pragma unroll
    for (int l = 0; l < 6; l++) acc[k][l] = 0.f;
  float sums[6];
  #pragma unroll
  for (int k = 0; k < 6; k++) sums[k] = 0.f;

  for (int lr = 0; lr < CROWS; lr++) {
    const int rowoff = lr * PH;
    for (int lc = g; lc < NHW; lc += 32) {
      float va[6], vb[6];
      #pragma unroll
      for (int k = 0; k < 6; k++) va[k] = baseA[k][rowoff + lc];
      #pragma unroll
      for (int k = 0; k < 6; k++) vb[k] = baseB[k][rowoff + lc];
      #pragma unroll
      for (int k = 0; k < 6; k++)
        #pragma unroll
        for (int l = 0; l < 6; l++) acc[k][l] = fmaf(va[k], vb[l], acc[k][l]);
      if (diag) {
        #pragma unroll
        for (int k = 0; k < 6; k++) sums[k] += va[k];
      }
    }
  }

  #pragma unroll
  for (int k = 0; k < 6; k++)
    #pragma unroll
    for (int l = 0; l < 6; l++) {
      float v = acc[k][l];
      #pragma unroll
      for (int m = 16; m >= 1; m >>= 1) v += __shfl_xor(v, m);
      acc[k][l] = v;
    }
  if (diag) {
    #pragma unroll
    for (int k = 0; k < 6; k++) {
      float v = sums[k];
      #pragma unroll
      for (int m = 16; m >= 1; m >>= 1) v += __shfl_xor(v, m);
      sums[k] = v;
    }
  }
  if (g == 0) {
    float* dst = cov + (size_t)bc * 324;
    #pragma unroll
    for (int k = 0; k < 6; k++)
      #pragma unroll
      for (int l = 0; l < 6; l++)
        atomicAdd(&dst[(6 * ta + k) * 18 + 6 * tb + l], acc[k][l]);
    if (diag) {
      #pragma unroll
      for (int k = 0; k < 6; k++)
        atomicAdd(&s1out[bc * 32 + 6 * ta + k], sums[k]);
    }
  }
}

// ---------------- kernel Solve: one wave per (b,c); center in DOUBLE --------
// raw upper-triangle at cov[min*18+max]; C(i,j) = raw(i,j) - n*mu_i*mu_j
__global__ __launch_bounds__(64)
void kSolve(const float* __restrict__ cov_all, const float* __restrict__ s1,
            float* __restrict__ acc) {
  const int bc   = blockIdx.x;
  const int lane = threadIdx.x;
  const float* cr = cov_all + (size_t)bc * 324;
  const double n = (double)NS;

  double mu[18];
  #pragma unroll
  for (int r = 0; r < 18; r++) mu[r] = (double)s1[bc * 32 + r] / n;
#define CC(i, j) ((double)cr[(i) * 18 + (j)] - n * mu[(i)] * mu[(j)])

  // --- Cholesky of P = pr_cov + 1e-3 I ; lane i holds row i (j<=i) ----------
  double row[9];
  #pragma unroll
  for (int j = 0; j < 9; j++)
    row[j] = (lane < 9 && j <= lane) ? CC(9 + j, 9 + lane) : 0.0;
  if (lane < 9) row[lane] += 1e-3;

  #pragma unroll
  for (int k = 0; k < 9; k++) {
    if (lane == k) {
      double s = row[k];
      #pragma unroll
      for (int m = 0; m < k; m++) s -= row[m] * row[m];
      row[k] = sqrt(fmax(s, 1e-300));
    }
    double rk[9];
    #pragma unroll
    for (int m = 0; m <= k; m++) rk[m] = __shfl(row[m], k);
    if (lane > k && lane < 9) {
      double s = row[k];
      #pragma unroll
      for (int m = 0; m < k; m++) s -= row[m] * rk[m];
      row[k] = s / rk[k];
    }
  }

  // --- gather full L into each lane -----------------------------------------
  double Lm[9][9];
  #pragma unroll
  for (int i = 0; i < 9; i++)
    #pragma unroll
    for (int m = 0; m <= i; m++) Lm[i][m] = __shfl(row[m], i);

  // --- lane c solves L * mc = B^T[:,c], B[c][r] = C(c, 9+r) -----------------
  double mc[9];
  #pragma unroll
  for (int r = 0; r < 9; r++) mc[r] = 0.0;
  if (lane < 9) {
    #pragma unroll
    for (int r = 0; r < 9; r++) {
      double s = CC(lane, 9 + r);
      #pragma unroll
      for (int m = 0; m < r; m++) s -= Lm[r][m] * mc[m];
      mc[r] = s / Lm[r][r];
    }
  }

  // --- A2[i][j] = C(j,i) - dot(m_i, m_j) (+1e-3 diag); lane i holds row i ---
  double a2[9];
  #pragma unroll
  for (int j = 0; j < 9; j++) a2[j] = 0.0;
  #pragma unroll
  for (int j = 0; j < 9; j++) {
    double mj[9];
    #pragma unroll
    for (int r = 0; r < 9; r++) mj[r] = __shfl(mc[r], j);
    double dot = 0.0;
    #pragma unroll
    for (int r = 0; r < 9; r++) dot += mc[r] * mj[r];
    if (lane < 9 && j <= lane)
      a2[j] = CC(j, lane) - dot + ((j == lane) ? 1e-3 : 0.0);
  }
#undef CC

  // --- second Cholesky + logdet ---------------------------------------------
  double myld = 0.0;
  #pragma unroll
  for (int k = 0; k < 9; k++) {
    if (lane == k) {
      double s = a2[k];
      #pragma unroll
      for (int m = 0; m < k; m++) s -= a2[m] * a2[m];
      double d = sqrt(fmax(s, 0.0));
      a2[k] = d;
      myld = 2.0 * log(d + 1e-8);
    }
    double rk[9];
    #pragma unroll
    for (int m = 0; m <= k; m++) rk[m] = __shfl(a2[m], k);
    if (lane > k && lane < 9) {
      double s = a2[k];
      #pragma unroll
      for (int m = 0; m < k; m++) s -= a2[m] * rk[m];
      a2[k] = s / rk[k];
    }
  }
  #pragma unroll
  for (int m = 32; m >= 1; m >>= 1) myld += __shfl_xor(myld, m);
  if (lane == 0) atomicAdd(&acc[4], (float)myld);
}

// ---------------- finalize ----------------------------------------------------
__global__ void kFin(const float* __restrict__ ws, float* __restrict__ out) {
  if (threadIdx.x == 0 && blockIdx.x == 0) {
    const double cnt = (double)ws[3];
    const double bce = 0.5 * ((double)ws[0] / (cnt * NF + 1e-8) +
                              (double)ws[1] / (cnt * NM + 1e-8) +
                              (double)ws[2] / (cnt * NHI + 1e-8));
    const double rmi = 0.5 * (double)ws[4] / (double)(NB * 9);
    out[0] = (float)(bce + rmi);
  }
}

extern "C" void kernel_launch(void* const* d_in, const int* in_sizes, int n_in,
                              void* d_out, int out_size, void* d_ws, size_t ws_size,
                              hipStream_t stream) {
  (void)in_sizes; (void)n_in; (void)out_size; (void)ws_size;
  const float* cls   = (const float*)d_in[3];
  const int*   label = (const int*)d_in[4];
  float* ws = (float*)d_ws;

  hipMemsetAsync(d_ws, 0, WS_ZERO_BYTES, stream);

  dim3 gA(5, 171, NB);
  kA<<<gA, 128, 0, stream>>>(cls, label, ws);
  kCov<<<NBC * NCH2, 192, 0, stream>>>(ws, ws + WS_COV, ws + WS_S1);
  kSolve<<<NBC, 64, 0, stream>>>(ws + WS_COV, ws + WS_S1, ws);
  kFin<<<1, 64, 0, stream>>>(ws, (float*)d_out);
}

// Round 6
// 132.223 us; speedup vs baseline: 3.6158x; 3.4050x over previous
//
#include <hip/hip_runtime.h>
#include <math.h>

namespace {
constexpr int NB = 4, NCHT = 29, NF = 19, NM = 7, NHI = 3;
constexpr int HH = 512, WW = 512;
constexpr int PH  = 170;           // pooled H/W (512-3)/3+1
constexpr int NHW = 168;           // shifted-view grid 170-3+1
constexpr int NS  = NHW * NHW;     // 28224 samples
constexpr int NBC = NB * NCHT;     // 116 (b,c) pairs
constexpr int CROWS = 14;          // sample rows per kCov chunk
constexpr int NCH2  = NHW / CROWS; // 12 chunks

constexpr int F2M[NF] = {0,0,0,1,1,1,2,2,3,3,4,5,5,6,6,6,6,6,6};
constexpr int M2H[NM] = {0,0,1,1,1,2,2};
constexpr int F2H[NF] = {0,0,0,0,0,0,1,1,1,1,1,2,2,2,2,2,2,2,2};

constexpr unsigned long long packTbl(const int* a, int n) {
  unsigned long long p = 0;
  for (int i = 0; i < n; i++) p |= (unsigned long long)(a[i]) << (3 * i);
  return p;
}
constexpr unsigned long long PF2M = packTbl(F2M, NF);
constexpr unsigned long long PF2H = packTbl(F2H, NF);

// ws float layout
// [4] = rmi accumulator (116 atomics, low contention — fine)
constexpr int    WS_S1  = 16;     // raw view sums, 116*32  -> [16, 3728)
constexpr int    WS_COV = 4096;   // raw upper-tri moments, 116*324 -> [4096, 41680)
constexpr int    WS_RED = 49152;  // 64 slots * 16 floats (64B-spread BCE partials)
constexpr size_t WS_LA  = 65536;
constexpr size_t WS_PR  = WS_LA + (size_t)NBC * PH * PH;
constexpr size_t WS_ZERO_BYTES = (size_t)(WS_RED + 64 * 16) * 4;
} // namespace

// ---------------- kernel A: per-column sigmoid + hierarchy + BCE + 3x3 pool --
// grid (5, 171, NB), block 128. Block bx owns windows [34bx,34bx+34) i.e.
// columns [102bx, 102bx+102); thread = one column. bx==4: tid 102,103
// cover BCE-only columns 510,511.
// BCE partial sums: block-reduce in LDS -> ONE atomicAdd set per block into
// one of 64 64B-spread slots (kills same-line atomic serialization, which
// was ~44ns/lane x 6840 lanes ≈ 300us in rounds 2-5).
__global__ __launch_bounds__(128, 2)
void kA(const float* __restrict__ cls, const int* __restrict__ label,
        float* __restrict__ ws) {
  const int bx  = blockIdx.x;
  const int wy  = blockIdx.y;
  const int b   = blockIdx.z;
  const int tid = threadIdx.x;

  __shared__ float    sPr[102][30];   // 29 used, stride 30
  __shared__ unsigned sMask[102];
  __shared__ float    sRed[4][2];

  float bce0 = 0.f, bce1 = 0.f, bce2 = 0.f, cnt = 0.f;

  const bool pool   = (tid < 102);
  const bool hasCol = pool || (bx == 4 && tid < 104);
  const bool row2   = (wy < 170);     // wy==170: only 2 real rows

  if (hasCol) {
    const int x  = 102 * bx + tid;
    const int y0 = 3 * wy;
    const size_t lpix = ((size_t)b * HH + y0) * WW + x;
    const int off2 = row2 ? 2 * WW : 0;   // safe dummy addr for wy==170
    const int l0 = label[lpix];
    const int l1 = label[lpix + WW];
    const int l2 = label[lpix + off2];

    const float* cp = cls + ((size_t)(b * NCHT) * HH + y0) * WW + x;
    float r0v[NCHT], r1v[NCHT], r2v[NCHT];
    #pragma unroll
    for (int c = 0; c < NCHT; c++) r0v[c] = cp[(size_t)c * HH * WW];
    #pragma unroll
    for (int c = 0; c < NCHT; c++) r1v[c] = cp[(size_t)c * HH * WW + WW];
    #pragma unroll
    for (int c = 0; c < NCHT; c++) r2v[c] = cp[(size_t)c * HH * WW + off2];

    float colPr[NCHT];
    #pragma unroll
    for (int c = 0; c < NCHT; c++) colPr[c] = 0.f;
    unsigned msk = 0u;

    auto doRow = [&](const float* rv, int lbl, bool act) {
      const bool valid = act && (lbl != 255);
      const int lf = valid ? lbl : 0;
      const int lm = (int)((PF2M >> (3 * lf)) & 7ull);
      const int lh = (int)((PF2H >> (3 * lf)) & 7ull);
      const float vm = valid ? 1.f : 0.f;

      float p[NCHT];
      #pragma unroll
      for (int c = 0; c < NCHT; c++)
        p[c] = __builtin_amdgcn_rcpf(1.f + __expf(-rv[c]));

      float segf[NM];
      #pragma unroll
      for (int m = 0; m < NM; m++) segf[m] = -1.f;
      #pragma unroll
      for (int f = 0; f < NF; f++) segf[F2M[f]] = fmaxf(segf[F2M[f]], p[f]);
      float pBc[NM];
      #pragma unroll
      for (int m = 0; m < NM; m++) pBc[m] = fmaxf(segf[m], p[NF + m]);
      float segm[NHI];
      #pragma unroll
      for (int k = 0; k < NHI; k++) segm[k] = -1.f;
      #pragma unroll
      for (int m = 0; m < NM; m++) segm[M2H[m]] = fmaxf(segm[M2H[m]], pBc[m]);
      float pCc[NHI];
      #pragma unroll
      for (int k = 0; k < NHI; k++) pCc[k] = fmaxf(segm[k], p[NF + NM + k]);

      // fine: pos = min(pA, pB[f2m]), neg = pA
      #pragma unroll
      for (int f = 0; f < NF; f++) {
        const float pos = fminf(p[f], p[NF + F2M[f]]);
        if (valid)
          bce0 += (f == lf) ? -__logf(pos + 1e-8f) : -__logf(1.f - p[f] + 1e-8f);
        colPr[f] = fmaxf(colPr[f], pos * vm + 1e-6f);
      }
      // mid: pos = min(pB, pC[m2h]), neg = pBc
      #pragma unroll
      for (int m = 0; m < NM; m++) {
        const float pos = fminf(p[NF + m], p[NF + NM + M2H[m]]);
        if (valid)
          bce1 += (m == lm) ? -__logf(pos + 1e-8f) : -__logf(1.f - pBc[m] + 1e-8f);
        colPr[NF + m] = fmaxf(colPr[NF + m], pos * vm + 1e-6f);
      }
      // high: pos = pC, neg = pCc
      #pragma unroll
      for (int k = 0; k < NHI; k++) {
        const float pos = p[NF + NM + k];
        if (valid)
          bce2 += (k == lh) ? -__logf(pos + 1e-8f) : -__logf(1.f - pCc[k] + 1e-8f);
        colPr[NF + NM + k] = fmaxf(colPr[NF + NM + k], pos * vm + 1e-6f);
      }
      if (valid) {
        msk |= 1u << lf;
        msk |= 1u << (19 + lm);
        msk |= 1u << (26 + lh);
      }
      cnt += vm;
    };

    doRow(r0v, l0, true);
    doRow(r1v, l1, true);
    doRow(r2v, l2, row2);

    if (pool) {
      sMask[tid] = msk;
      #pragma unroll
      for (int c = 0; c < NCHT; c++) sPr[tid][c] = colPr[c];
    }
  }

  // wave-level reduce of BCE partials (before barrier so sRed write is ready)
  #pragma unroll
  for (int m = 32; m >= 1; m >>= 1) {
    bce0 += __shfl_xor(bce0, m);
    bce1 += __shfl_xor(bce1, m);
    bce2 += __shfl_xor(bce2, m);
    cnt  += __shfl_xor(cnt, m);
  }
  {
    const int wave = tid >> 6, lane = tid & 63;
    if (lane == 0) {
      sRed[0][wave] = bce0; sRed[1][wave] = bce1;
      sRed[2][wave] = bce2; sRed[3][wave] = cnt;
    }
  }
  __syncthreads();

  if (row2 && tid < 34) {
    const int wx = 34 * bx + tid;
    const int c0 = 3 * tid;
    float* la = ws + WS_LA;
    float* pr = ws + WS_PR;
    const unsigned m = sMask[c0] | sMask[c0 + 1] | sMask[c0 + 2];
    const size_t base = ((size_t)(b * NCHT) * PH + wy) * PH + wx;
    #pragma unroll
    for (int c = 0; c < NF; c++)
      la[base + (size_t)c * PH * PH] = (float)((m >> c) & 1u);
    #pragma unroll
    for (int mm = 0; mm < NM; mm++)
      la[base + (size_t)(NF + mm) * PH * PH] = (float)((m >> (19 + mm)) & 1u);
    #pragma unroll
    for (int k = 0; k < NHI; k++)
      la[base + (size_t)(NF + NM + k) * PH * PH] = (float)((m >> (26 + k)) & 1u);
    #pragma unroll
    for (int c = 0; c < NCHT; c++)
      pr[base + (size_t)c * PH * PH] =
          fmaxf(fmaxf(sPr[c0][c], sPr[c0 + 1][c]), sPr[c0 + 2][c]);
  }

  if (tid == 0) {
    const int slot = (bx + 5 * (wy + 171 * b)) & 63;
    float* dst = ws + WS_RED + slot * 16;
    atomicAdd(&dst[0], sRed[0][0] + sRed[0][1]);
    atomicAdd(&dst[1], sRed[1][0] + sRed[1][1]);
    atomicAdd(&dst[2], sRed[2][0] + sRed[2][1]);
    atomicAdd(&dst[3], sRed[3][0] + sRed[3][1]);
  }
}

// ---------------- kernel Cov: RAW 18x18 moments + view sums, LDS stencil ----
// The 9 "views" of a plane are a 3x3 stencil: stage 16 plane rows in LDS once,
// read shifted. block = (bc, 14-row chunk), 192 thr = 6 tile-groups x 32.
__global__ __launch_bounds__(192)
void kCov(const float* __restrict__ ws_base, float* __restrict__ cov,
          float* __restrict__ s1out) {
  const int bc    = blockIdx.x / NCH2;
  const int chunk = blockIdx.x % NCH2;
  const int tid   = threadIdx.x;
  const int tile  = tid / 32;
  const int g     = tid % 32;
  // tiles: 0:(0,0) 1:(0,1) 2:(0,2) 3:(1,1) 4:(1,2) 5:(2,2)
  const int ta = (tile < 3) ? 0 : ((tile < 5) ? 1 : 2);
  const int tb = (tile < 3) ? tile : ((tile < 5) ? tile - 2 : 2);
  const bool diag = (ta == tb);

  __shared__ float sA[16 * PH];
  __shared__ float sP[16 * PH];

  const int r0 = chunk * CROWS;
  const float* Ag = ws_base + WS_LA + (size_t)bc * PH * PH + (size_t)r0 * PH;
  const float* Pg = ws_base + WS_PR + (size_t)bc * PH * PH + (size_t)r0 * PH;
  for (int i = tid; i < 16 * PH; i += 192) { sA[i] = Ag[i]; sP[i] = Pg[i]; }
  __syncthreads();

  // view r: plane (r<9 ? A : P), row-offset (r%9)/3, col-offset (r%9)%3
  const float* baseA[6];
  const float* baseB[6];
  #pragma unroll
  for (int k = 0; k < 6; k++) {
    int r = 6 * ta + k, rr = r % 9;
    baseA[k] = ((r < 9) ? sA : sP) + (rr / 3) * PH + (rr % 3);
    int r2 = 6 * tb + k, rr2 = r2 % 9;
    baseB[k] = ((r2 < 9) ? sA : sP) + (rr2 / 3) * PH + (rr2 % 3);
  }

  float acc[6][6];
  #pragma unroll
  for (int k = 0; k < 6; k++)
    #pragma unroll
    for (int l = 0; l < 6; l++) acc[k][l] = 0.f;
  float sums[6];
  #pragma unroll
  for (int k = 0; k < 6; k++) sums[k] = 0.f;

  for (int lr = 0; lr < CROWS; lr++) {
    const int rowoff = lr * PH;
    for (int lc = g; lc < NHW; lc += 32) {
      float va[6], vb[6];
      #pragma unroll
      for (int k = 0; k < 6; k++) va[k] = baseA[k][rowoff + lc];
      #pragma unroll
      for (int k = 0; k < 6; k++) vb[k] = baseB[k][rowoff + lc];
      #pragma unroll
      for (int k = 0; k < 6; k++)
        #pragma unroll
        for (int l = 0; l < 6; l++) acc[k][l] = fmaf(va[k], vb[l], acc[k][l]);
      if (diag) {
        #pragma unroll
        for (int k = 0; k < 6; k++) sums[k] += va[k];
      }
    }
  }

  #pragma unroll
  for (int k = 0; k < 6; k++)
    #pragma unroll
    for (int l = 0; l < 6; l++) {
      float v = acc[k][l];
      #pragma unroll
      for (int m = 16; m >= 1; m >>= 1) v += __shfl_xor(v, m);
      acc[k][l] = v;
    }
  if (diag) {
    #pragma unroll
    for (int k = 0; k < 6; k++) {
      float v = sums[k];
      #pragma unroll
      for (int m = 16; m >= 1; m >>= 1) v += __shfl_xor(v, m);
      sums[k] = v;
    }
  }
  if (g == 0) {
    float* dst = cov + (size_t)bc * 324;
    #pragma unroll
    for (int k = 0; k < 6; k++)
      #pragma unroll
      for (int l = 0; l < 6; l++)
        atomicAdd(&dst[(6 * ta + k) * 18 + 6 * tb + l], acc[k][l]);
    if (diag) {
      #pragma unroll
      for (int k = 0; k < 6; k++)
        atomicAdd(&s1out[bc * 32 + 6 * ta + k], sums[k]);
    }
  }
}

// ---------------- kernel Solve: one wave per (b,c); center in DOUBLE --------
// raw upper-triangle at cov[min*18+max]; C(i,j) = raw(i,j) - n*mu_i*mu_j
__global__ __launch_bounds__(64)
void kSolve(const float* __restrict__ cov_all, const float* __restrict__ s1,
            float* __restrict__ acc) {
  const int bc   = blockIdx.x;
  const int lane = threadIdx.x;
  const float* cr = cov_all + (size_t)bc * 324;
  const double n = (double)NS;

  double mu[18];
  #pragma unroll
  for (int r = 0; r < 18; r++) mu[r] = (double)s1[bc * 32 + r] / n;
#define CC(i, j) ((double)cr[(i) * 18 + (j)] - n * mu[(i)] * mu[(j)])

  // --- Cholesky of P = pr_cov + 1e-3 I ; lane i holds row i (j<=i) ----------
  double row[9];
  #pragma unroll
  for (int j = 0; j < 9; j++)
    row[j] = (lane < 9 && j <= lane) ? CC(9 + j, 9 + lane) : 0.0;
  if (lane < 9) row[lane] += 1e-3;

  #pragma unroll
  for (int k = 0; k < 9; k++) {
    if (lane == k) {
      double s = row[k];
      #pragma unroll
      for (int m = 0; m < k; m++) s -= row[m] * row[m];
      row[k] = sqrt(fmax(s, 1e-300));
    }
    double rk[9];
    #pragma unroll
    for (int m = 0; m <= k; m++) rk[m] = __shfl(row[m], k);
    if (lane > k && lane < 9) {
      double s = row[k];
      #pragma unroll
      for (int m = 0; m < k; m++) s -= row[m] * rk[m];
      row[k] = s / rk[k];
    }
  }

  // --- gather full L into each lane -----------------------------------------
  double Lm[9][9];
  #pragma unroll
  for (int i = 0; i < 9; i++)
    #pragma unroll
    for (int m = 0; m <= i; m++) Lm[i][m] = __shfl(row[m], i);

  // --- lane c solves L * mc = B^T[:,c], B[c][r] = C(c, 9+r) -----------------
  double mc[9];
  #pragma unroll
  for (int r = 0; r < 9; r++) mc[r] = 0.0;
  if (lane < 9) {
    #pragma unroll
    for (int r = 0; r < 9; r++) {
      double s = CC(lane, 9 + r);
      #pragma unroll
      for (int m = 0; m < r; m++) s -= Lm[r][m] * mc[m];
      mc[r] = s / Lm[r][r];
    }
  }

  // --- A2[i][j] = C(j,i) - dot(m_i, m_j) (+1e-3 diag); lane i holds row i ---
  double a2[9];
  #pragma unroll
  for (int j = 0; j < 9; j++) a2[j] = 0.0;
  #pragma unroll
  for (int j = 0; j < 9; j++) {
    double mj[9];
    #pragma unroll
    for (int r = 0; r < 9; r++) mj[r] = __shfl(mc[r], j);
    double dot = 0.0;
    #pragma unroll
    for (int r = 0; r < 9; r++) dot += mc[r] * mj[r];
    if (lane < 9 && j <= lane)
      a2[j] = CC(j, lane) - dot + ((j == lane) ? 1e-3 : 0.0);
  }
#undef CC

  // --- second Cholesky + logdet ---------------------------------------------
  double myld = 0.0;
  #pragma unroll
  for (int k = 0; k < 9; k++) {
    if (lane == k) {
      double s = a2[k];
      #pragma unroll
      for (int m = 0; m < k; m++) s -= a2[m] * a2[m];
      double d = sqrt(fmax(s, 0.0));
      a2[k] = d;
      myld = 2.0 * log(d + 1e-8);
    }
    double rk[9];
    #pragma unroll
    for (int m = 0; m <= k; m++) rk[m] = __shfl(a2[m], k);
    if (lane > k && lane < 9) {
      double s = a2[k];
      #pragma unroll
      for (int m = 0; m < k; m++) s -= a2[m] * rk[m];
      a2[k] = s / rk[k];
    }
  }
  #pragma unroll
  for (int m = 32; m >= 1; m >>= 1) myld += __shfl_xor(myld, m);
  if (lane == 0) atomicAdd(&acc[4], (float)myld);
}

// ---------------- finalize: reduce 64 BCE slots + combine --------------------
__global__ void kFin(const float* __restrict__ ws, float* __restrict__ out) {
  const int tid = threadIdx.x;
  const float* slot = ws + WS_RED + tid * 16;
  float b0 = slot[0], b1 = slot[1], b2 = slot[2], b3 = slot[3];
  #pragma unroll
  for (int m = 32; m >= 1; m >>= 1) {
    b0 += __shfl_xor(b0, m);
    b1 += __shfl_xor(b1, m);
    b2 += __shfl_xor(b2, m);
    b3 += __shfl_xor(b3, m);
  }
  if (tid == 0) {
    const double cnt = (double)b3;
    const double bce = 0.5 * ((double)b0 / (cnt * NF + 1e-8) +
                              (double)b1 / (cnt * NM + 1e-8) +
                              (double)b2 / (cnt * NHI + 1e-8));
    const double rmi = 0.5 * (double)ws[4] / (double)(NB * 9);
    out[0] = (float)(bce + rmi);
  }
}

extern "C" void kernel_launch(void* const* d_in, const int* in_sizes, int n_in,
                              void* d_out, int out_size, void* d_ws, size_t ws_size,
                              hipStream_t stream) {
  (void)in_sizes; (void)n_in; (void)out_size; (void)ws_size;
  const float* cls   = (const float*)d_in[3];
  const int*   label = (const int*)d_in[4];
  float* ws = (float*)d_ws;

  hipMemsetAsync(d_ws, 0, WS_ZERO_BYTES, stream);

  dim3 gA(5, 171, NB);
  kA<<<gA, 128, 0, stream>>>(cls, label, ws);
  kCov<<<NBC * NCH2, 192, 0, stream>>>(ws, ws + WS_COV, ws + WS_S1);
  kSolve<<<NBC, 64, 0, stream>>>(ws + WS_COV, ws + WS_S1, ws);
  kFin<<<1, 64, 0, stream>>>(ws, (float*)d_out);
}